// Round 8
// baseline (11734.986 us; speedup 1.0000x reference)
//
#include <hip/hip_runtime.h>
#include <hip/hip_bf16.h>

#define BB   1024
#define TT   64
#define IND  64
#define HH   512
#define G4   2048   // 4*H
#define NLAYER 8
#define NCLS 128
#define KP   1024   // packed W k-stride: k<512 = W_hh, k>=512 = W_ih (layer0 64 + pad)
#define CH   4      // G chunk (timesteps precomputed per proj phase)

typedef __bf16 bf16x8 __attribute__((ext_vector_type(8)));
typedef __bf16 bf16x4 __attribute__((ext_vector_type(4)));
typedef float  f32x4  __attribute__((ext_vector_type(4)));

typedef const __attribute__((address_space(1))) void* as1cvp;
typedef __attribute__((address_space(3))) void* as3vp;

__device__ __forceinline__ void gload16(void* lds, const void* g) {
  __builtin_amdgcn_global_load_lds((as1cvp)g, (as3vp)lds, 16, 0, 0);
}

__device__ __forceinline__ float sigmf(float x) { return 1.f / (1.f + __expf(-x)); }
__device__ __forceinline__ float tanhfast(float x) { return 2.f / (1.f + __expf(-2.f * x)) - 1.f; }

// ---------------- prep kernels ----------------
__global__ void cvt_kernel(const float* __restrict__ s, __bf16* __restrict__ d, int n) {
  int i = blockIdx.x * 256 + threadIdx.x;
  if (i < n) d[i] = (__bf16)s[i];
}

__global__ void pack_w(const float* __restrict__ whh0, const float* __restrict__ wih0,
                       const float* __restrict__ whh, const float* __restrict__ wih,
                       __bf16* __restrict__ Wp) {
  int i = blockIdx.x * 256 + threadIdx.x;  // 8*2048*1024
  int k = i & (KP - 1), n = (i >> 10) & 2047, l = i >> 21;
  float v;
  if (k < 512) v = (l == 0) ? whh0[n * 512 + k] : whh[((size_t)(l - 1) * G4 + n) * 512 + k];
  else if (l == 0) v = (k < 512 + IND) ? wih0[n * IND + (k - 512)] : 0.f;
  else v = wih[((size_t)(l - 1) * G4 + n) * 512 + (k - 512)];
  Wp[i] = (__bf16)v;
}

__global__ void bias_prep(const float* __restrict__ bi0, const float* __restrict__ bh0,
                          const float* __restrict__ bi, const float* __restrict__ bh,
                          float* __restrict__ biasb) {
  int i = blockIdx.x * 256 + threadIdx.x;  // 8*2048
  int l = i >> 11, k = i & 2047;
  float v = (l == 0) ? (bi0[k] + bh0[k]) : (bi[(l - 1) * G4 + k] + bh[(l - 1) * G4 + k]);
  biasb[i] = v;
}

__global__ void zero_u32(unsigned* __restrict__ p, int n) {
  int i = blockIdx.x * 256 + threadIdx.x;
  if (i < n) p[i] = 0u;
}

// ---------------- persistent fused LSTM layer ----------------
// R8: tile 64b x 64n (16 j x 4 gates), 64KB LDS W_hh -> grid 512, 2 blocks/CU
// (3x64KB > 160KB LDS), 2 waves/SIMD. XCD k owns bx {2k,2k+1} x all 32 by ->
// recurrent chain is XCD-local (h produced+consumed in one L2).
// Per CH-step chunk: proj phase computes G = bias + x*W_ih^T for the block's
// own cells into a block-private 32KB global region (lane-private flat layout,
// stays dirty in the local L2). Step loop: G-init (pre-spin) -> agent-scope
// relaxed poll (sc-bits correct -> no stale L1) -> 16 h-frag loads -> 64 MFMA
// -> cell update (c in regs) -> plain h store -> __syncthreads (vmcnt drain)
// -> relaxed agent release.
template <int NKX>
__global__ __launch_bounds__(256, 2) void layer_kernel(
    const __bf16* __restrict__ xseq,    // prev-layer h [T][B][512] (NKX=16)
    const float* __restrict__ xf,       // raw x [B][T][64]        (NKX=2)
    __bf16* __restrict__ Hout,
    const __bf16* __restrict__ Wl,      // packed W [2048][KP]
    const float* __restrict__ bias,     // [2048]
    __bf16* __restrict__ Gbuf,          // [512 regions][CH*4096]
    unsigned* __restrict__ cnt,         // [16*64] per-bx counters, 256B stride
    unsigned* __restrict__ xslot) {     // [8] per-XCD slot counters
  extern __shared__ __bf16 Wlds[];      // 64KB = 16 k-slices x (64 rows x 32 k)
  __shared__ int sb[2];
  __shared__ unsigned sv;
  const int tid = threadIdx.x;

  if (tid == 0) {
    unsigned xcc;
    asm volatile("s_getreg_b32 %0, hwreg(HW_REG_XCC_ID)" : "=s"(xcc));
    xcc &= 7u;
    unsigned slot = __hip_atomic_fetch_add(xslot + xcc, 1u, __ATOMIC_RELAXED,
                                           __HIP_MEMORY_SCOPE_AGENT) & 63u;
    sb[0] = (int)((xcc << 1) | (slot >> 5));  // bx 0..15 (XCD-local pair)
    sb[1] = (int)(slot & 31);                 // by 0..31
  }
  __syncthreads();
  const int bx = sb[0], by = sb[1];
  const int b0 = bx << 6, j0 = by << 4;

  const int lane = tid & 63, wv = tid >> 6;
  const int qr = lane >> 4, ml = lane & 15;

  // ---- stage W_hh (64 n-rows x 512 k) into LDS, XOR-swizzled
  for (int it = 0; it < 16; ++it) {
    const int p = it * 256 + tid;           // granule 0..4095
    const int kt = p >> 8;                  // k-slice 0..15
    const int q = p & 255;
    const int u = q >> 2;                   // lds row 0..63 (gate*16 + jj)
    const int g = (q & 3) ^ ((u >> 1) & 3); // source k-quad
    const int n = ((u >> 4) << 9) + j0 + (u & 15);
    gload16(&Wlds[p * 8], Wl + (size_t)n * KP + kt * 32 + g * 8);
  }

  const __bf16* wb[4];
  float bv[4];
  int wsw[4];
#pragma unroll
  for (int g = 0; g < 4; ++g) {
    const int n = g * 512 + j0 + ml;
    wb[g] = Wl + (size_t)n * KP + 512 + qr * 8;   // W_ih (L2-resident)
    bv[g] = bias[n];
    const int u = g * 16 + ml;
    wsw[g] = u * 32 + ((qr ^ ((u >> 1) & 3)) << 3);  // + kt*2048
  }
  const int r0 = b0 + (wv << 4);          // wave's 16 rows
  const int rb = r0 + (qr << 2);          // C-frag row base (4 rows)
  const int jcol = j0 + ml;
  __bf16* Gblk = Gbuf + (size_t)(bx * 32 + by) * (CH * 4096);
  float c4[4] = {0.f, 0.f, 0.f, 0.f};

  __syncthreads();  // W_hh staged (barrier drains vmcnt)

  for (int c = 0; c < TT / CH; ++c) {
    const int tb = c * CH;
    // ---- proj phase: G = bias + x*W_ih^T for CH(=4) steps, self-produced
    {
      f32x4 pacc[4][4];
#pragma unroll
      for (int m = 0; m < 4; ++m)
#pragma unroll
        for (int g = 0; g < 4; ++g)
#pragma unroll
          for (int r = 0; r < 4; ++r) pacc[m][g][r] = bv[g];
#pragma unroll
      for (int kt = 0; kt < NKX; ++kt) {
        bf16x8 am[4];
#pragma unroll
        for (int m = 0; m < 4; ++m) {
          if constexpr (NKX == 2) {
            const float* xr =
                xf + ((size_t)(r0 + ml) * TT + (tb + m)) * IND + kt * 32 + qr * 8;
            const f32x4 f0 = *(const f32x4*)xr;
            const f32x4 f1 = *(const f32x4*)(xr + 4);
            bf16x8 a;
#pragma unroll
            for (int r = 0; r < 4; ++r) {
              a[r] = (__bf16)f0[r];
              a[4 + r] = (__bf16)f1[r];
            }
            am[m] = a;
          } else {
            am[m] = *(const bf16x8*)(xseq + ((size_t)(tb + m) * BB + r0 + ml) * HH +
                                     kt * 32 + qr * 8);
          }
        }
#pragma unroll
        for (int g = 0; g < 4; ++g) {
          const bf16x8 wf = *(const bf16x8*)(wb[g] + kt * 32);
#pragma unroll
          for (int m = 0; m < 4; ++m)
            pacc[m][g] = __builtin_amdgcn_mfma_f32_16x16x32_bf16(am[m], wf, pacc[m][g], 0, 0, 0);
        }
      }
#pragma unroll
      for (int m = 0; m < 4; ++m)
#pragma unroll
        for (int g = 0; g < 4; ++g) {
          bf16x4 gv;
#pragma unroll
          for (int r = 0; r < 4; ++r) gv[r] = (__bf16)pacc[m][g][r];
          // lane-private flat layout; round-trips identically in G-init
          *(bf16x4*)&Gblk[(size_t)(m * 16 + wv * 4 + g) * 256 + lane * 4] = gv;
        }
    }

    // ---- step loop
    for (int ts = 0; ts < CH; ++ts) {
      const int t = tb + ts;
      f32x4 acc[4];
#pragma unroll
      for (int g = 0; g < 4; ++g) {  // G init (no spin dependence)
        const bf16x4 gv =
            *(const bf16x4*)&Gblk[(size_t)(ts * 16 + wv * 4 + g) * 256 + lane * 4];
#pragma unroll
        for (int r = 0; r < 4; ++r) acc[g][r] = (float)gv[r];
      }
      if (t > 0) {
        if (tid == 0) {
          const unsigned tgt = (unsigned)(t << 5);  // 32 producers per step
          unsigned v = __hip_atomic_load(cnt + bx * 64, __ATOMIC_RELAXED,
                                         __HIP_MEMORY_SCOPE_AGENT);
          while (v < tgt) {
            __builtin_amdgcn_s_sleep(1);
            v = __hip_atomic_load(cnt + bx * 64, __ATOMIC_RELAXED,
                                  __HIP_MEMORY_SCOPE_AGENT);
          }
          sv = v;
        }
        __syncthreads();
        // (sv>>20)==0 at runtime; keeps h loads ordered after the spin.
        const __bf16* hp = Hout + (size_t)(t - 1) * BB * HH + (sv >> 20);
        const __bf16* a = hp + (size_t)(r0 + ml) * HH + qr * 8;
        bf16x8 ah[16];
#pragma unroll
        for (int kt = 0; kt < 16; ++kt) ah[kt] = *(const bf16x8*)(a + kt * 32);
#pragma unroll
        for (int kt = 0; kt < 16; ++kt) {
#pragma unroll
          for (int g = 0; g < 4; ++g) {
            const bf16x8 wf = *(const bf16x8*)&Wlds[kt * 2048 + wsw[g]];
            acc[g] = __builtin_amdgcn_mfma_f32_16x16x32_bf16(ah[kt], wf, acc[g], 0, 0, 0);
          }
        }
      }
      // ---- cell update + h store (plain stores; consumers are same-XCD)
      __bf16* ho = Hout + (size_t)t * BB * HH;
#pragma unroll
      for (int r = 0; r < 4; ++r) {
        const float gi = sigmf(acc[0][r]);
        const float gf = sigmf(acc[1][r]);
        const float gg = tanhfast(acc[2][r]);
        const float go = sigmf(acc[3][r]);
        const float cv = gf * c4[r] + gi * gg;
        c4[r] = cv;
        ho[(size_t)(rb + r) * HH + jcol] = (__bf16)(go * tanhfast(cv));
      }
      if (t < TT - 1) {
        __syncthreads();  // drains vmcnt(0): h visible before release
        if (tid == 0)
          __hip_atomic_fetch_add(cnt + bx * 64, 1u, __ATOMIC_RELAXED,
                                 __HIP_MEMORY_SCOPE_AGENT);
      }
    }
  }
}

// ---------------- FC (bf16 MFMA, K-split) ----------------
__global__ __launch_bounds__(256, 2) void fc_kernel(
    const __bf16* __restrict__ hseq, const __bf16* __restrict__ fcw,
    float* __restrict__ partial) {
  __shared__ __bf16 At[64 * 32];
  __shared__ __bf16 Wt[128 * 32];
  const int tid = threadIdx.x;
  const int b0 = blockIdx.x * 64;
  const int kbase = blockIdx.y * 2048;
  const int lane = tid & 63, wv = tid >> 6;
  const int qr = lane >> 4, ml = lane & 15;
  const int wr = (wv >> 1) * 32, wc = (wv & 1) * 64;
  const int sr = tid >> 2, sk = (tid & 3) * 8;

  f32x4 acc[2][4];
  for (int i = 0; i < 2; i++)
    for (int j = 0; j < 4; j++)
      for (int r = 0; r < 4; r++) acc[i][j][r] = 0.f;

  for (int kt = 0; kt < 64; ++kt) {
    const int k = kbase + kt * 32;
    const int t = k >> 9;
    const int jb = k & 511;
    gload16(&At[tid * 8],        hseq + ((size_t)t * BB + b0 + sr) * HH + jb + sk);
    gload16(&Wt[tid * 8],        fcw + (size_t)sr * (TT * HH) + k + sk);
    gload16(&Wt[2048 + tid * 8], fcw + (size_t)(sr + 64) * (TT * HH) + k + sk);
    __syncthreads();
    bf16x8 af[2], bfr[4];
    for (int i = 0; i < 2; i++) af[i]  = *(const bf16x8*)&At[(wr + i * 16 + ml) * 32 + qr * 8];
    for (int j = 0; j < 4; j++) bfr[j] = *(const bf16x8*)&Wt[(wc + j * 16 + ml) * 32 + qr * 8];
    for (int i = 0; i < 2; i++)
      for (int j = 0; j < 4; j++)
        acc[i][j] = __builtin_amdgcn_mfma_f32_16x16x32_bf16(af[i], bfr[j], acc[i][j], 0, 0, 0);
    __syncthreads();
  }
  for (int i = 0; i < 2; i++)
    for (int j = 0; j < 4; j++)
      for (int r = 0; r < 4; r++)
        partial[((size_t)blockIdx.y * BB + b0 + wr + i * 16 + qr * 4 + r) * NCLS + wc + j * 16 + ml] =
            acc[i][j][r];
}

__global__ void fc_reduce(const float* __restrict__ partial, const float* __restrict__ fcb,
                          float* __restrict__ out) {
  int i = blockIdx.x * 256 + threadIdx.x;  // B*128
  float s = fcb[i & 127];
  for (int p = 0; p < 16; p++) s += partial[(size_t)p * (BB * NCLS) + i];
  out[i] = s;
}

// ---------------- host ----------------
extern "C" void kernel_launch(void* const* d_in, const int* in_sizes, int n_in,
                              void* d_out, int out_size, void* d_ws, size_t ws_size,
                              hipStream_t stream) {
  const float* x    = (const float*)d_in[0];
  const float* wih0 = (const float*)d_in[1];
  const float* whh0 = (const float*)d_in[2];
  const float* bih0 = (const float*)d_in[3];
  const float* bhh0 = (const float*)d_in[4];
  const float* wih  = (const float*)d_in[5];
  const float* whh  = (const float*)d_in[6];
  const float* bih  = (const float*)d_in[7];
  const float* bhh  = (const float*)d_in[8];
  const float* fcw  = (const float*)d_in[9];
  const float* fcb  = (const float*)d_in[10];
  float* out = (float*)d_out;

  hipFuncSetAttribute((const void*)layer_kernel<2>,
                      hipFuncAttributeMaxDynamicSharedMemorySize, 65536);
  hipFuncSetAttribute((const void*)layer_kernel<16>,
                      hipFuncAttributeMaxDynamicSharedMemorySize, 65536);

  size_t off = 0;
  char* base = (char*)d_ws;
  auto carve = [&](size_t bytes) -> char* {
    char* p = base + off;
    off += (bytes + 255) & ~(size_t)255;
    return p;
  };
  // total ~193 MB (= R6's proven budget; Gbuf aliases the FC partial buffer)
  __bf16*   Wp    = (__bf16*)carve((size_t)NLAYER * G4 * KP * 2);      // 33.6 MB
  __bf16*   fcwb  = (__bf16*)carve((size_t)NCLS * TT * HH * 2);        //  8.4 MB
  float*    biasb = (float*)carve((size_t)NLAYER * G4 * 4);
  __bf16*   hseqA = (__bf16*)carve((size_t)TT * BB * HH * 2);          // 67.1 MB
  __bf16*   hseqB = (__bf16*)carve((size_t)TT * BB * HH * 2);          // 67.1 MB
  char*     gpu_u = carve((size_t)512 * CH * 4096 * 2);                // 16.8 MB
  __bf16*   Gbuf  = (__bf16*)gpu_u;          // used during layers
  float*    part  = (float*)gpu_u;           // used after layers (8.4 MB < 16.8)
  unsigned* cnt   = (unsigned*)carve((size_t)NLAYER * 16 * 64 * 4);
  unsigned* xslot = (unsigned*)carve((size_t)NLAYER * 8 * 4);

  // prep
  pack_w<<<(NLAYER * G4 * KP) / 256, 256, 0, stream>>>(whh0, wih0, whh, wih, Wp);
  cvt_kernel<<<(NCLS * TT * HH) / 256, 256, 0, stream>>>(fcw, fcwb, NCLS * TT * HH);
  bias_prep<<<(NLAYER * G4) / 256, 256, 0, stream>>>(bih0, bhh0, bih, bhh, biasb);
  zero_u32<<<(NLAYER * 16 * 64 + 255) / 256, 256, 0, stream>>>(cnt, NLAYER * 16 * 64);
  zero_u32<<<1, 256, 0, stream>>>(xslot, NLAYER * 8);

  for (int l = 0; l < NLAYER; ++l) {
    const __bf16* xs = (l & 1) ? hseqA : hseqB;   // prev-layer h (l>=1)
    __bf16* Ho = (l & 1) ? hseqB : hseqA;
    const __bf16* Wl = Wp + (size_t)l * G4 * KP;
    const float* bl = biasb + l * G4;
    unsigned* cl = cnt + (size_t)l * 16 * 64;
    unsigned* xl = xslot + l * 8;
    if (l == 0)
      layer_kernel<2><<<512, 256, 65536, stream>>>(nullptr, x, Ho, Wl, bl, Gbuf, cl, xl);
    else
      layer_kernel<16><<<512, 256, 65536, stream>>>(xs, nullptr, Ho, Wl, bl, Gbuf, cl, xl);
  }
  const __bf16* hfinal = hseqB;  // layer 7 (odd) writes hseqB
  fc_kernel<<<dim3(16, 16), 256, 0, stream>>>(hfinal, fcwb, part);
  fc_reduce<<<(BB * NCLS) / 256, 256, 0, stream>>>(part, fcb, out);
}

// Round 9
// 8314.971 us; speedup vs baseline: 1.4113x; 1.4113x over previous
//
#include <hip/hip_runtime.h>
#include <hip/hip_bf16.h>

#define BB   1024
#define TT   64
#define IND  64
#define HH   512
#define G4   2048   // 4*H
#define NLAYER 8
#define NCLS 128
#define KP   1024   // packed W k-stride: k<512 = W_hh, k>=512 = W_ih (layer0 64 + pad)
#define RS   8      // ring slots per layer (reuse distance 8 > fence gap 4)

typedef __bf16 bf16x8 __attribute__((ext_vector_type(8)));
typedef float  f32x4  __attribute__((ext_vector_type(4)));

typedef const __attribute__((address_space(1))) void* as1cvp;
typedef __attribute__((address_space(3))) void* as3vp;

__device__ __forceinline__ void gload16(void* lds, const void* g) {
  __builtin_amdgcn_global_load_lds((as1cvp)g, (as3vp)lds, 16, 0, 0);
}

__device__ __forceinline__ float sigmf(float x) { return 1.f / (1.f + __expf(-x)); }
__device__ __forceinline__ float tanhfast(float x) { return 2.f / (1.f + __expf(-2.f * x)) - 1.f; }

// ---------------- prep kernels ----------------
__global__ void cvt_kernel(const float* __restrict__ s, __bf16* __restrict__ d, int n) {
  int i = blockIdx.x * 256 + threadIdx.x;
  if (i < n) d[i] = (__bf16)s[i];
}

__global__ void pack_w(const float* __restrict__ whh0, const float* __restrict__ wih0,
                       const float* __restrict__ whh, const float* __restrict__ wih,
                       __bf16* __restrict__ Wp) {
  int i = blockIdx.x * 256 + threadIdx.x;  // 8*2048*1024
  int k = i & (KP - 1), n = (i >> 10) & 2047, l = i >> 21;
  float v;
  if (k < 512) v = (l == 0) ? whh0[n * 512 + k] : whh[((size_t)(l - 1) * G4 + n) * 512 + k];
  else if (l == 0) v = (k < 512 + IND) ? wih0[n * IND + (k - 512)] : 0.f;
  else v = wih[((size_t)(l - 1) * G4 + n) * 512 + (k - 512)];
  Wp[i] = (__bf16)v;
}

__global__ void bias_prep(const float* __restrict__ bi0, const float* __restrict__ bh0,
                          const float* __restrict__ bi, const float* __restrict__ bh,
                          float* __restrict__ biasb) {
  int i = blockIdx.x * 256 + threadIdx.x;  // 8*2048
  int l = i >> 11, k = i & 2047;
  float v = (l == 0) ? (bi0[k] + bh0[k]) : (bi[(l - 1) * G4 + k] + bh[(l - 1) * G4 + k]);
  biasb[i] = v;
}

__global__ void zero_u32(unsigned* __restrict__ p, int n) {
  int i = blockIdx.x * 256 + threadIdx.x;
  if (i < n) p[i] = 0u;
}

// ---------------- all-layers pipelined LSTM ----------------
// Grid 512 x 256thr, 64KB LDS -> 2 blocks/CU (pigeonhole), 64 blocks/XCD.
// XCD k = layer k (claimed via XCC_ID): block = (layer, bx=slot>>5, by=slot&31),
// tile = 512 b-rows x 64 n-cols (4 gates x 16 j). W_hh in LDS; c in regs.
// Pipeline: (l,t) needs (l-1,t) and (l,t-1): 71 supersteps total.
// h rings: layers 0..6 RS=8 slots; layer 7 writes full h7 for FC.
// Sync: per-(l,bx,by) step flags (plain agent stores, no RMW). Wave0 polls
// 32 own + 32 upstream flags in ONE 64-lane load + __all ballot.
// Coherence: h stores agent write-through (LLC); fence(acquire,agent) every
// 4 steps -> ring reuse distance 8 > 4 guarantees no stale L1/L2 line.
__global__ __launch_bounds__(256, 2) void lstm_all(
    const float* __restrict__ xf,      // [B][T][64] fp32
    const __bf16* __restrict__ Wp,     // [8][2048][KP]
    const float* __restrict__ biasb,   // [8][2048]
    __bf16* __restrict__ hring,        // [7][RS][B][512]
    __bf16* __restrict__ h7,           // [64][B][512]
    unsigned* __restrict__ flags,      // [8][2][64] (32 used per group)
    unsigned* __restrict__ xslot) {    // [8]
  extern __shared__ __bf16 Wlds[];     // 64KB: 16 k-slices x (64 rows x 32 k)
  __shared__ int sbs;
  const int tid = threadIdx.x;

  if (tid == 0) {
    unsigned xcc;
    asm volatile("s_getreg_b32 %0, hwreg(HW_REG_XCC_ID)" : "=s"(xcc));
    xcc &= 7u;
    unsigned slot = __hip_atomic_fetch_add(xslot + xcc, 1u, __ATOMIC_RELAXED,
                                           __HIP_MEMORY_SCOPE_AGENT) & 63u;
    sbs = (int)((xcc << 6) | slot);
  }
  __syncthreads();
  const int l  = sbs >> 6;         // layer = XCD
  const int bx = (sbs >> 5) & 1;   // b-half (512 rows)
  const int by = sbs & 31;         // j-tile (16 j x 4 gates)
  const int j0 = by << 4;
  const __bf16* Wl = Wp + (size_t)l * G4 * KP;

  // ---- stage W_hh (64 n-rows x 512 k) into LDS, XOR-swizzled
  for (int it = 0; it < 16; ++it) {
    const int p = it * 256 + tid;           // granule 0..4095
    const int kt = p >> 8;
    const int q = p & 255;
    const int u = q >> 2;                   // row 0..63 (gate*16+jj)
    const int g = (q & 3) ^ ((u >> 1) & 3);
    const int n = ((u >> 4) << 9) + j0 + (u & 15);
    gload16(&Wlds[p * 8], Wl + (size_t)n * KP + kt * 32 + g * 8);
  }

  const int lane = tid & 63, wv = tid >> 6;
  const int qr = lane >> 4, ml = lane & 15;
  const __bf16* wb[4];
  float bv[4];
  int wsw[4];
#pragma unroll
  for (int g = 0; g < 4; ++g) {
    const int n = g * 512 + j0 + ml;
    wb[g] = Wl + (size_t)n * KP + 512 + qr * 8;   // W_ih (L2-resident on this XCD)
    bv[g] = biasb[l * G4 + n];
    const int u = g * 16 + ml;
    wsw[g] = u * 32 + ((qr ^ ((u >> 1) & 3)) << 3);
  }
  const int r0 = (bx << 9) + (wv << 7);   // wave's 128 rows (8 m-tiles)
  const int rowA = r0 + ml;
  __bf16* ringL = hring + (size_t)l * RS * BB * HH;                      // l<7
  const __bf16* ringU = hring + (size_t)((l > 0 ? l : 1) - 1) * RS * BB * HH;
  unsigned* ownf = flags + (l * 2 + bx) * 64;
  unsigned* upf  = flags + ((l > 0 ? l - 1 : 0) * 2 + bx) * 64;
  unsigned* dnf  = flags + ((l < 7 ? l + 1 : 7) * 2 + bx) * 64;
  float c8[8][4] = {};
  __syncthreads();  // W_hh staged (barrier drains lds-load counters)

  for (int t = 0; t < TT; ++t) {
    // ---- B1: combined wait (own >= t, upstream >= t+1), wave 0 only
    if (wv == 0) {
      const bool isown = (lane < 32);
      const unsigned* fp = isown ? (ownf + lane) : (upf + (lane - 32));
      const unsigned need = isown ? (unsigned)t : (unsigned)(t + 1);
      const bool act = isown ? (t > 0) : (l > 0);
      for (;;) {
        unsigned v = act ? __hip_atomic_load(fp, __ATOMIC_RELAXED,
                                             __HIP_MEMORY_SCOPE_AGENT)
                         : need;
        if (__all((int)(v >= need))) break;
        __builtin_amdgcn_s_sleep(1);
      }
    }
    __syncthreads();
    if ((t & 3) == 0) __builtin_amdgcn_fence(__ATOMIC_ACQUIRE, "agent");

    // ---- acc init + x-part (input = h^{l-1}[t], or raw x for l=0)
    f32x4 acc[8][4];
#pragma unroll
    for (int m = 0; m < 8; ++m)
#pragma unroll
      for (int g = 0; g < 4; ++g)
#pragma unroll
        for (int r = 0; r < 4; ++r) acc[m][g][r] = bv[g];

    if (l == 0) {
#pragma unroll
      for (int m = 0; m < 8; ++m) {
        const float* xr = xf + ((size_t)(rowA + m * 16) * TT + t) * IND + qr * 8;
        const f32x4 f0 = *(const f32x4*)xr;
        const f32x4 f1 = *(const f32x4*)(xr + 4);
        const f32x4 f2 = *(const f32x4*)(xr + 32);
        const f32x4 f3 = *(const f32x4*)(xr + 36);
        bf16x8 a0, a1;
#pragma unroll
        for (int r = 0; r < 4; ++r) {
          a0[r] = (__bf16)f0[r]; a0[4 + r] = (__bf16)f1[r];
          a1[r] = (__bf16)f2[r]; a1[4 + r] = (__bf16)f3[r];
        }
#pragma unroll
        for (int g = 0; g < 4; ++g) {
          acc[m][g] = __builtin_amdgcn_mfma_f32_16x16x32_bf16(
              a0, *(const bf16x8*)(wb[g]), acc[m][g], 0, 0, 0);
          acc[m][g] = __builtin_amdgcn_mfma_f32_16x16x32_bf16(
              a1, *(const bf16x8*)(wb[g] + 32), acc[m][g], 0, 0, 0);
        }
      }
    } else {
      const __bf16* src = ringU + (size_t)(t & (RS - 1)) * BB * HH;
#pragma unroll
      for (int m = 0; m < 8; ++m) {
        const __bf16* a = src + (size_t)(rowA + m * 16) * HH + qr * 8;
#pragma unroll
        for (int half = 0; half < 2; ++half) {
          bf16x8 ah[8];
#pragma unroll
          for (int k8 = 0; k8 < 8; ++k8)
            ah[k8] = *(const bf16x8*)(a + (half * 8 + k8) * 32);
#pragma unroll
          for (int k8 = 0; k8 < 8; ++k8) {
            const int kt = half * 8 + k8;
#pragma unroll
            for (int g = 0; g < 4; ++g)
              acc[m][g] = __builtin_amdgcn_mfma_f32_16x16x32_bf16(
                  ah[k8], *(const bf16x8*)(wb[g] + kt * 32), acc[m][g], 0, 0, 0);
          }
        }
      }
    }

    // ---- h-part (t>0): A = own h[t-1], W_hh from LDS
    if (t > 0) {
      const __bf16* srcH = (l < 7) ? ringL + (size_t)((t - 1) & (RS - 1)) * BB * HH
                                   : h7 + (size_t)(t - 1) * BB * HH;
#pragma unroll
      for (int m = 0; m < 8; ++m) {
        const __bf16* a = srcH + (size_t)(rowA + m * 16) * HH + qr * 8;
#pragma unroll
        for (int half = 0; half < 2; ++half) {
          bf16x8 ah[8];
#pragma unroll
          for (int k8 = 0; k8 < 8; ++k8)
            ah[k8] = *(const bf16x8*)(a + (half * 8 + k8) * 32);
#pragma unroll
          for (int k8 = 0; k8 < 8; ++k8) {
            const int kt = half * 8 + k8;
#pragma unroll
            for (int g = 0; g < 4; ++g)
              acc[m][g] = __builtin_amdgcn_mfma_f32_16x16x32_bf16(
                  ah[k8], *(const bf16x8*)&Wlds[kt * 2048 + wsw[g]], acc[m][g], 0, 0, 0);
          }
        }
      }
    }

    // ---- ring back-pressure (overwrite slot t&7 only after downstream read gen t-8)
    if (wv == 0 && l < 7 && t >= RS) {
      const unsigned need = (unsigned)(t - (RS - 1));
      for (;;) {
        unsigned v = (lane < 32) ? __hip_atomic_load(dnf + lane, __ATOMIC_RELAXED,
                                                     __HIP_MEMORY_SCOPE_AGENT)
                                 : need;
        if (__all((int)(v >= need))) break;
        __builtin_amdgcn_s_sleep(1);
      }
    }
    __syncthreads();  // B2

    // ---- activations + h store (agent write-through -> LLC visible)
    unsigned short* dst = (unsigned short*)((l < 7)
        ? ringL + (size_t)(t & (RS - 1)) * BB * HH
        : h7 + (size_t)t * BB * HH);
#pragma unroll
    for (int m = 0; m < 8; ++m) {
      const int rbm = r0 + m * 16 + (qr << 2);
#pragma unroll
      for (int r = 0; r < 4; ++r) {
        const float gi = sigmf(acc[m][0][r]);
        const float gf = sigmf(acc[m][1][r]);
        const float gg = tanhfast(acc[m][2][r]);
        const float go = sigmf(acc[m][3][r]);
        const float cv = gf * c8[m][r] + gi * gg;
        c8[m][r] = cv;
        const __bf16 hv = (__bf16)(go * tanhfast(cv));
        __hip_atomic_store(dst + (size_t)(rbm + r) * HH + (j0 + ml),
                           __builtin_bit_cast(unsigned short, hv),
                           __ATOMIC_RELAXED, __HIP_MEMORY_SCOPE_AGENT);
      }
    }
    __syncthreads();  // B3: drains vmcnt -> stores at coherence point
    if (tid == 0)
      __hip_atomic_store(ownf + by, (unsigned)(t + 1), __ATOMIC_RELAXED,
                         __HIP_MEMORY_SCOPE_AGENT);
  }
}

// ---------------- FC (bf16 MFMA, K-split) ----------------
__global__ __launch_bounds__(256, 2) void fc_kernel(
    const __bf16* __restrict__ hseq, const __bf16* __restrict__ fcw,
    float* __restrict__ partial) {
  __shared__ __bf16 At[64 * 32];
  __shared__ __bf16 Wt[128 * 32];
  const int tid = threadIdx.x;
  const int b0 = blockIdx.x * 64;
  const int kbase = blockIdx.y * 2048;
  const int lane = tid & 63, wv = tid >> 6;
  const int qr = lane >> 4, ml = lane & 15;
  const int wr = (wv >> 1) * 32, wc = (wv & 1) * 64;
  const int sr = tid >> 2, sk = (tid & 3) * 8;

  f32x4 acc[2][4];
  for (int i = 0; i < 2; i++)
    for (int j = 0; j < 4; j++)
      for (int r = 0; r < 4; r++) acc[i][j][r] = 0.f;

  for (int kt = 0; kt < 64; ++kt) {
    const int k = kbase + kt * 32;
    const int t = k >> 9;
    const int jb = k & 511;
    gload16(&At[tid * 8],        hseq + ((size_t)t * BB + b0 + sr) * HH + jb + sk);
    gload16(&Wt[tid * 8],        fcw + (size_t)sr * (TT * HH) + k + sk);
    gload16(&Wt[2048 + tid * 8], fcw + (size_t)(sr + 64) * (TT * HH) + k + sk);
    __syncthreads();
    bf16x8 af[2], bfr[4];
    for (int i = 0; i < 2; i++) af[i]  = *(const bf16x8*)&At[(wr + i * 16 + ml) * 32 + qr * 8];
    for (int j = 0; j < 4; j++) bfr[j] = *(const bf16x8*)&Wt[(wc + j * 16 + ml) * 32 + qr * 8];
    for (int i = 0; i < 2; i++)
      for (int j = 0; j < 4; j++)
        acc[i][j] = __builtin_amdgcn_mfma_f32_16x16x32_bf16(af[i], bfr[j], acc[i][j], 0, 0, 0);
    __syncthreads();
  }
  for (int i = 0; i < 2; i++)
    for (int j = 0; j < 4; j++)
      for (int r = 0; r < 4; r++)
        partial[((size_t)blockIdx.y * BB + b0 + wr + i * 16 + qr * 4 + r) * NCLS + wc + j * 16 + ml] =
            acc[i][j][r];
}

__global__ void fc_reduce(const float* __restrict__ partial, const float* __restrict__ fcb,
                          float* __restrict__ out) {
  int i = blockIdx.x * 256 + threadIdx.x;  // B*128
  float s = fcb[i & 127];
  for (int p = 0; p < 16; p++) s += partial[(size_t)p * (BB * NCLS) + i];
  out[i] = s;
}

// ---------------- host ----------------
extern "C" void kernel_launch(void* const* d_in, const int* in_sizes, int n_in,
                              void* d_out, int out_size, void* d_ws, size_t ws_size,
                              hipStream_t stream) {
  const float* x    = (const float*)d_in[0];
  const float* wih0 = (const float*)d_in[1];
  const float* whh0 = (const float*)d_in[2];
  const float* bih0 = (const float*)d_in[3];
  const float* bhh0 = (const float*)d_in[4];
  const float* wih  = (const float*)d_in[5];
  const float* whh  = (const float*)d_in[6];
  const float* bih  = (const float*)d_in[7];
  const float* bhh  = (const float*)d_in[8];
  const float* fcw  = (const float*)d_in[9];
  const float* fcb  = (const float*)d_in[10];
  float* out = (float*)d_out;

  hipFuncSetAttribute((const void*)lstm_all,
                      hipFuncAttributeMaxDynamicSharedMemorySize, 65536);

  size_t off = 0;
  char* base = (char*)d_ws;
  auto carve = [&](size_t bytes) -> char* {
    char* p = base + off;
    off += (bytes + 255) & ~(size_t)255;
    return p;
  };
  // total ~176 MB (< R6's proven 193 MB budget)
  __bf16*   Wp    = (__bf16*)carve((size_t)NLAYER * G4 * KP * 2);      // 33.6 MB
  __bf16*   fcwb  = (__bf16*)carve((size_t)NCLS * TT * HH * 2);        //  8.4 MB
  float*    biasb = (float*)carve((size_t)NLAYER * G4 * 4);
  __bf16*   hring = (__bf16*)carve((size_t)7 * RS * BB * HH * 2);      // 58.7 MB
  __bf16*   h7    = (__bf16*)carve((size_t)TT * BB * HH * 2);          // 67.1 MB
  float*    part  = (float*)carve((size_t)16 * BB * NCLS * 4);         //  8.4 MB
  unsigned* flags = (unsigned*)carve((size_t)(NLAYER * 2 * 64 + 64) * 4);
  unsigned* xslot = flags + NLAYER * 2 * 64;

  // prep
  pack_w<<<(NLAYER * G4 * KP) / 256, 256, 0, stream>>>(whh0, wih0, whh, wih, Wp);
  cvt_kernel<<<(NCLS * TT * HH) / 256, 256, 0, stream>>>(fcw, fcwb, NCLS * TT * HH);
  bias_prep<<<(NLAYER * G4) / 256, 256, 0, stream>>>(bih0, bhh0, bih, bhh, biasb);
  zero_u32<<<(NLAYER * 2 * 64 + 64 + 255) / 256, 256, 0, stream>>>(
      flags, NLAYER * 2 * 64 + 64);

  lstm_all<<<512, 256, 65536, stream>>>(x, Wp, biasb, hring, h7, flags, xslot);

  fc_kernel<<<dim3(16, 16), 256, 0, stream>>>(h7, fcwb, part);
  fc_reduce<<<(BB * NCLS) / 256, 256, 0, stream>>>(part, fcb, out);
}

// Round 10
// 4773.716 us; speedup vs baseline: 2.4582x; 1.7418x over previous
//
#include <hip/hip_runtime.h>
#include <hip/hip_bf16.h>

#define BB   1024
#define TT   64
#define IND  64
#define HH   512
#define G4   2048   // 4*H
#define NLAYER 8
#define NCLS 128
#define KP   1024   // packed W k-stride: k<512 = W_hh, k>=512 = W_ih (layer0 64 + pad)
#define RS   8      // ring slots per layer (reuse distance 8 = fence period)
#define SLOT (32 * 1024 * 16)  // elements per h slot: [by=32][b=1024][jj=16]

typedef __bf16 bf16x8 __attribute__((ext_vector_type(8)));
typedef float  f32x4  __attribute__((ext_vector_type(4)));

typedef const __attribute__((address_space(1))) void* as1cvp;
typedef __attribute__((address_space(3))) void* as3vp;

__device__ __forceinline__ void gload16(void* lds, const void* g) {
  __builtin_amdgcn_global_load_lds((as1cvp)g, (as3vp)lds, 16, 0, 0);
}

__device__ __forceinline__ float sigmf(float x) { return 1.f / (1.f + __expf(-x)); }
__device__ __forceinline__ float tanhfast(float x) { return 2.f / (1.f + __expf(-2.f * x)) - 1.f; }

// ---------------- prep kernels ----------------
__global__ void cvt_kernel(const float* __restrict__ s, __bf16* __restrict__ d, int n) {
  int i = blockIdx.x * 256 + threadIdx.x;
  if (i < n) d[i] = (__bf16)s[i];
}

__global__ void pack_w(const float* __restrict__ whh0, const float* __restrict__ wih0,
                       const float* __restrict__ whh, const float* __restrict__ wih,
                       __bf16* __restrict__ Wp) {
  int i = blockIdx.x * 256 + threadIdx.x;  // 8*2048*1024
  int k = i & (KP - 1), n = (i >> 10) & 2047, l = i >> 21;
  float v;
  if (k < 512) v = (l == 0) ? whh0[n * 512 + k] : whh[((size_t)(l - 1) * G4 + n) * 512 + k];
  else if (l == 0) v = (k < 512 + IND) ? wih0[n * IND + (k - 512)] : 0.f;
  else v = wih[((size_t)(l - 1) * G4 + n) * 512 + (k - 512)];
  Wp[i] = (__bf16)v;
}

__global__ void bias_prep(const float* __restrict__ bi0, const float* __restrict__ bh0,
                          const float* __restrict__ bi, const float* __restrict__ bh,
                          float* __restrict__ biasb) {
  int i = blockIdx.x * 256 + threadIdx.x;  // 8*2048
  int l = i >> 11, k = i & 2047;
  float v = (l == 0) ? (bi0[k] + bh0[k]) : (bi[(l - 1) * G4 + k] + bh[(l - 1) * G4 + k]);
  biasb[i] = v;
}

__global__ void zero_u32(unsigned* __restrict__ p, int n) {
  int i = blockIdx.x * 256 + threadIdx.x;
  if (i < n) p[i] = 0u;
}

// ---------------- all-layers pipelined LSTM ----------------
// Grid 512 x 256thr, 64KB LDS -> 2 blocks/CU, 64 blocks/XCD. XCD k = layer k.
// Block = (layer, bx=b-half, by=j-tile); tile 512b x 64n (4 gates x 16 j).
// h layout (R10): [slot][by][1024 b][16 jj] -> wave stores are 4x32B
// CONTIGUOUS granules (kills the R9 12x write-through RMW amplification);
// consumer A-frag = aligned 16B load at base + kt*64KB + m*512B.
// Fence (acquire, agent) every RS=8 steps: any ring address re-read at t was
// last read at t-8 -> exactly one fence in (t-8, t] -> no stale L1/L2 line.
__global__ __launch_bounds__(256, 2) void lstm_all(
    const float* __restrict__ xf,      // [B][T][64] fp32
    const __bf16* __restrict__ Wp,     // [8][2048][KP]
    const float* __restrict__ biasb,   // [8][2048]
    __bf16* __restrict__ hring,        // [7][RS][SLOT]
    __bf16* __restrict__ h7,           // [64][SLOT]
    unsigned* __restrict__ flags,      // [8][2][64] (32 used per group)
    unsigned* __restrict__ xslot) {    // [8]
  extern __shared__ __bf16 Wlds[];     // 64KB: 16 k-slices x (64 rows x 32 k)
  __shared__ int sbs;
  const int tid = threadIdx.x;

  if (tid == 0) {
    unsigned xcc;
    asm volatile("s_getreg_b32 %0, hwreg(HW_REG_XCC_ID)" : "=s"(xcc));
    xcc &= 7u;
    unsigned slot = __hip_atomic_fetch_add(xslot + xcc, 1u, __ATOMIC_RELAXED,
                                           __HIP_MEMORY_SCOPE_AGENT) & 63u;
    sbs = (int)((xcc << 6) | slot);
  }
  __syncthreads();
  const int l  = sbs >> 6;         // layer = XCD
  const int bx = (sbs >> 5) & 1;   // b-half (512 rows)
  const int by = sbs & 31;         // j-tile (16 j x 4 gates)
  const int j0 = by << 4;
  const __bf16* Wl = Wp + (size_t)l * G4 * KP;

  // ---- stage W_hh (64 n-rows x 512 k) into LDS, XOR-swizzled
  for (int it = 0; it < 16; ++it) {
    const int p = it * 256 + tid;           // granule 0..4095
    const int kt = p >> 8;
    const int q = p & 255;
    const int u = q >> 2;                   // row 0..63 (gate*16+jj)
    const int g = (q & 3) ^ ((u >> 1) & 3);
    const int n = ((u >> 4) << 9) + j0 + (u & 15);
    gload16(&Wlds[p * 8], Wl + (size_t)n * KP + kt * 32 + g * 8);
  }

  const int lane = tid & 63, wv = tid >> 6;
  const int qr = lane >> 4, ml = lane & 15;
  const __bf16* wb[4];
  float bv[4];
  int wsw[4];
#pragma unroll
  for (int g = 0; g < 4; ++g) {
    const int n = g * 512 + j0 + ml;
    wb[g] = Wl + (size_t)n * KP + 512 + qr * 8;   // W_ih (L2-resident on this XCD)
    bv[g] = biasb[l * G4 + n];
    const int u = g * 16 + ml;
    wsw[g] = u * 32 + ((qr ^ ((u >> 1) & 3)) << 3);
  }
  const int r0 = (bx << 9) + (wv << 7);   // wave's 128 rows (8 m-tiles of 16)
  const int rowA = r0 + ml;
  // A-frag base offset into a slot: (kt*2 + (qr>>1))*16384 + row*16 + (qr&1)*8
  const int abase = ((qr >> 1) << 14) + rowA * 16 + ((qr & 1) << 3);
  __bf16* ringL = hring + (size_t)l * RS * SLOT;                       // l<7
  const __bf16* ringU = hring + (size_t)((l > 0 ? l : 1) - 1) * RS * SLOT;
  unsigned* ownf = flags + (l * 2 + bx) * 64;
  unsigned* upf  = flags + ((l > 0 ? l - 1 : 0) * 2 + bx) * 64;
  unsigned* dnf  = flags + ((l < 7 ? l + 1 : 7) * 2 + bx) * 64;
  float c8[8][4] = {};
  __syncthreads();  // W_hh staged

  for (int t = 0; t < TT; ++t) {
    // ---- B1: combined wait (own >= t, upstream >= t+1), wave 0 only
    if (wv == 0) {
      const bool isown = (lane < 32);
      const unsigned* fp = isown ? (ownf + lane) : (upf + (lane - 32));
      const unsigned need = isown ? (unsigned)t : (unsigned)(t + 1);
      const bool act = isown ? (t > 0) : (l > 0);
      for (;;) {
        unsigned v = act ? __hip_atomic_load(fp, __ATOMIC_RELAXED,
                                             __HIP_MEMORY_SCOPE_AGENT)
                         : need;
        if (__all((int)(v >= need))) break;
        __builtin_amdgcn_s_sleep(1);
      }
    }
    __syncthreads();
    if (t > 0 && (t & (RS - 1)) == 0)
      __builtin_amdgcn_fence(__ATOMIC_ACQUIRE, "agent");  // once per ring period

    // ---- acc init + x-part (input = h^{l-1}[t], or raw x for l=0)
    f32x4 acc[8][4];
#pragma unroll
    for (int m = 0; m < 8; ++m)
#pragma unroll
      for (int g = 0; g < 4; ++g)
#pragma unroll
        for (int r = 0; r < 4; ++r) acc[m][g][r] = bv[g];

    if (l == 0) {
#pragma unroll
      for (int m = 0; m < 8; ++m) {
        const float* xr = xf + ((size_t)(rowA + m * 16) * TT + t) * IND + qr * 8;
        const f32x4 f0 = *(const f32x4*)xr;
        const f32x4 f1 = *(const f32x4*)(xr + 4);
        const f32x4 f2 = *(const f32x4*)(xr + 32);
        const f32x4 f3 = *(const f32x4*)(xr + 36);
        bf16x8 a0, a1;
#pragma unroll
        for (int r = 0; r < 4; ++r) {
          a0[r] = (__bf16)f0[r]; a0[4 + r] = (__bf16)f1[r];
          a1[r] = (__bf16)f2[r]; a1[4 + r] = (__bf16)f3[r];
        }
#pragma unroll
        for (int g = 0; g < 4; ++g) {
          acc[m][g] = __builtin_amdgcn_mfma_f32_16x16x32_bf16(
              a0, *(const bf16x8*)(wb[g]), acc[m][g], 0, 0, 0);
          acc[m][g] = __builtin_amdgcn_mfma_f32_16x16x32_bf16(
              a1, *(const bf16x8*)(wb[g] + 32), acc[m][g], 0, 0, 0);
        }
      }
    } else {
      const __bf16* src = ringU + (size_t)(t & (RS - 1)) * SLOT + abase;
#pragma unroll
      for (int kt = 0; kt < 16; ++kt) {
        const __bf16* ak = src + kt * 32768;
        bf16x8 am[8];
#pragma unroll
        for (int m = 0; m < 8; ++m) am[m] = *(const bf16x8*)(ak + m * 256);
        bf16x8 wf[4];
#pragma unroll
        for (int g = 0; g < 4; ++g) wf[g] = *(const bf16x8*)(wb[g] + kt * 32);
#pragma unroll
        for (int m = 0; m < 8; ++m)
#pragma unroll
          for (int g = 0; g < 4; ++g)
            acc[m][g] = __builtin_amdgcn_mfma_f32_16x16x32_bf16(am[m], wf[g], acc[m][g], 0, 0, 0);
      }
    }

    // ---- h-part (t>0): A = own h[t-1], W_hh from LDS
    if (t > 0) {
      const __bf16* srcH = ((l < 7) ? ringL + (size_t)((t - 1) & (RS - 1)) * SLOT
                                    : h7 + (size_t)(t - 1) * SLOT) + abase;
#pragma unroll
      for (int kt = 0; kt < 16; ++kt) {
        const __bf16* ak = srcH + kt * 32768;
        bf16x8 am[8];
#pragma unroll
        for (int m = 0; m < 8; ++m) am[m] = *(const bf16x8*)(ak + m * 256);
        bf16x8 wf[4];
#pragma unroll
        for (int g = 0; g < 4; ++g) wf[g] = *(const bf16x8*)&Wlds[kt * 2048 + wsw[g]];
#pragma unroll
        for (int m = 0; m < 8; ++m)
#pragma unroll
          for (int g = 0; g < 4; ++g)
            acc[m][g] = __builtin_amdgcn_mfma_f32_16x16x32_bf16(am[m], wf[g], acc[m][g], 0, 0, 0);
      }
    }

    // ---- ring back-pressure (overwrite slot t&7 only after downstream read gen t-8)
    if (wv == 0 && l < 7 && t >= RS) {
      const unsigned need = (unsigned)(t - (RS - 1));
      for (;;) {
        unsigned v = (lane < 32) ? __hip_atomic_load(dnf + lane, __ATOMIC_RELAXED,
                                                     __HIP_MEMORY_SCOPE_AGENT)
                                 : need;
        if (__all((int)(v >= need))) break;
        __builtin_amdgcn_s_sleep(1);
      }
    }
    __syncthreads();  // B2

    // ---- activations + h store: [by][b][16] panel -> contiguous 32B granules
    unsigned short* dst = (unsigned short*)(((l < 7)
        ? ringL + (size_t)(t & (RS - 1)) * SLOT
        : h7 + (size_t)t * SLOT) + ((size_t)by << 14)) + ml;
#pragma unroll
    for (int m = 0; m < 8; ++m) {
      const int rbm = r0 + m * 16 + (qr << 2);
#pragma unroll
      for (int r = 0; r < 4; ++r) {
        const float gi = sigmf(acc[m][0][r]);
        const float gf = sigmf(acc[m][1][r]);
        const float gg = tanhfast(acc[m][2][r]);
        const float go = sigmf(acc[m][3][r]);
        const float cv = gf * c8[m][r] + gi * gg;
        c8[m][r] = cv;
        const __bf16 hv = (__bf16)(go * tanhfast(cv));
        __hip_atomic_store(dst + (size_t)(rbm + r) * 16,
                           __builtin_bit_cast(unsigned short, hv),
                           __ATOMIC_RELAXED, __HIP_MEMORY_SCOPE_AGENT);
      }
    }
    __syncthreads();  // B3: drains vmcnt -> stores at coherence point
    if (tid == 0)
      __hip_atomic_store(ownf + by, (unsigned)(t + 1), __ATOMIC_RELAXED,
                         __HIP_MEMORY_SCOPE_AGENT);
  }
}

// ---------------- FC (bf16 MFMA, K-split; h7 in [t][by][b][16] layout) ----------------
__global__ __launch_bounds__(256, 2) void fc_kernel(
    const __bf16* __restrict__ hseq, const __bf16* __restrict__ fcw,
    float* __restrict__ partial) {
  __shared__ __bf16 At[64 * 32];
  __shared__ __bf16 Wt[128 * 32];
  const int tid = threadIdx.x;
  const int b0 = blockIdx.x * 64;
  const int kbase = blockIdx.y * 2048;
  const int lane = tid & 63, wv = tid >> 6;
  const int qr = lane >> 4, ml = lane & 15;
  const int wr = (wv >> 1) * 32, wc = (wv & 1) * 64;
  const int sr = tid >> 2, sk = (tid & 3) * 8;

  f32x4 acc[2][4];
  for (int i = 0; i < 2; i++)
    for (int j = 0; j < 4; j++)
      for (int r = 0; r < 4; r++) acc[i][j][r] = 0.f;

  for (int kt = 0; kt < 64; ++kt) {
    const int k = kbase + kt * 32;
    const int t = k >> 9;
    const int kk = (k & 511) + sk;      // global j index of this 8-elem chunk
    gload16(&At[tid * 8],
            hseq + (size_t)t * SLOT + ((size_t)(kk >> 4) * 1024 + b0 + sr) * 16 + (kk & 15));
    gload16(&Wt[tid * 8],        fcw + (size_t)sr * (TT * HH) + k + sk);
    gload16(&Wt[2048 + tid * 8], fcw + (size_t)(sr + 64) * (TT * HH) + k + sk);
    __syncthreads();
    bf16x8 af[2], bfr[4];
    for (int i = 0; i < 2; i++) af[i]  = *(const bf16x8*)&At[(wr + i * 16 + ml) * 32 + qr * 8];
    for (int j = 0; j < 4; j++) bfr[j] = *(const bf16x8*)&Wt[(wc + j * 16 + ml) * 32 + qr * 8];
    for (int i = 0; i < 2; i++)
      for (int j = 0; j < 4; j++)
        acc[i][j] = __builtin_amdgcn_mfma_f32_16x16x32_bf16(af[i], bfr[j], acc[i][j], 0, 0, 0);
    __syncthreads();
  }
  for (int i = 0; i < 2; i++)
    for (int j = 0; j < 4; j++)
      for (int r = 0; r < 4; r++)
        partial[((size_t)blockIdx.y * BB + b0 + wr + i * 16 + qr * 4 + r) * NCLS + wc + j * 16 + ml] =
            acc[i][j][r];
}

__global__ void fc_reduce(const float* __restrict__ partial, const float* __restrict__ fcb,
                          float* __restrict__ out) {
  int i = blockIdx.x * 256 + threadIdx.x;  // B*128
  float s = fcb[i & 127];
  for (int p = 0; p < 16; p++) s += partial[(size_t)p * (BB * NCLS) + i];
  out[i] = s;
}

// ---------------- host ----------------
extern "C" void kernel_launch(void* const* d_in, const int* in_sizes, int n_in,
                              void* d_out, int out_size, void* d_ws, size_t ws_size,
                              hipStream_t stream) {
  const float* x    = (const float*)d_in[0];
  const float* wih0 = (const float*)d_in[1];
  const float* whh0 = (const float*)d_in[2];
  const float* bih0 = (const float*)d_in[3];
  const float* bhh0 = (const float*)d_in[4];
  const float* wih  = (const float*)d_in[5];
  const float* whh  = (const float*)d_in[6];
  const float* bih  = (const float*)d_in[7];
  const float* bhh  = (const float*)d_in[8];
  const float* fcw  = (const float*)d_in[9];
  const float* fcb  = (const float*)d_in[10];
  float* out = (float*)d_out;

  hipFuncSetAttribute((const void*)lstm_all,
                      hipFuncAttributeMaxDynamicSharedMemorySize, 65536);

  size_t off = 0;
  char* base = (char*)d_ws;
  auto carve = [&](size_t bytes) -> char* {
    char* p = base + off;
    off += (bytes + 255) & ~(size_t)255;
    return p;
  };
  // total ~176 MB (< proven 193 MB budget)
  __bf16*   Wp    = (__bf16*)carve((size_t)NLAYER * G4 * KP * 2);      // 33.6 MB
  __bf16*   fcwb  = (__bf16*)carve((size_t)NCLS * TT * HH * 2);        //  8.4 MB
  float*    biasb = (float*)carve((size_t)NLAYER * G4 * 4);
  __bf16*   hring = (__bf16*)carve((size_t)7 * RS * SLOT * 2);         // 58.7 MB
  __bf16*   h7    = (__bf16*)carve((size_t)TT * SLOT * 2);             // 67.1 MB
  float*    part  = (float*)carve((size_t)16 * BB * NCLS * 4);         //  8.4 MB
  unsigned* flags = (unsigned*)carve((size_t)(NLAYER * 2 * 64 + 64) * 4);
  unsigned* xslot = flags + NLAYER * 2 * 64;

  // prep
  pack_w<<<(NLAYER * G4 * KP) / 256, 256, 0, stream>>>(whh0, wih0, whh, wih, Wp);
  cvt_kernel<<<(NCLS * TT * HH) / 256, 256, 0, stream>>>(fcw, fcwb, NCLS * TT * HH);
  bias_prep<<<(NLAYER * G4) / 256, 256, 0, stream>>>(bih0, bhh0, bih, bhh, biasb);
  zero_u32<<<(NLAYER * 2 * 64 + 64 + 255) / 256, 256, 0, stream>>>(
      flags, NLAYER * 2 * 64 + 64);

  lstm_all<<<512, 256, 65536, stream>>>(x, Wp, biasb, hring, h7, flags, xslot);

  fc_kernel<<<dim3(16, 16), 256, 0, stream>>>(h7, fcwb, part);
  fc_reduce<<<(BB * NCLS) / 256, 256, 0, stream>>>(part, fcb, out);
}